// Round 2
// baseline (1783.517 us; speedup 1.0000x reference)
//
#include <hip/hip_runtime.h>
#include <math.h>

#define BB  2
#define SS  2048
#define DD  1024
#define HH  16
#define DHH 64
#define RK  16
#define NR  33          // 2*RK+1
#define BH  (BB*HH)     // 32
#define MT  (BB*SS)     // 4096
#define NT  (SS/64)     // 32

typedef unsigned char u8;

__device__ __forceinline__ float4 ld4(const float* p){ return *reinterpret_cast<const float4*>(p); }
__device__ __forceinline__ void st4(float* p, float4 v){ *reinterpret_cast<float4*>(p) = v; }

// ---------------- K1: fused QKV projection (fp32 tiled GEMM) ----------------
// C[m,e] = sum_d X[m,d]*W[e,d] + bias[e]; stored (b,h,s,dh); q pre-scaled 1/8.
__launch_bounds__(256)
__global__ void proj_qkv_kernel(const float* __restrict__ query,
                                const float* __restrict__ key,
                                const float* __restrict__ value,
                                const float* __restrict__ Wq, const float* __restrict__ bq,
                                const float* __restrict__ Wk, const float* __restrict__ bk,
                                const float* __restrict__ Wv, const float* __restrict__ bv,
                                const u8* __restrict__ q_mask,
                                const u8* __restrict__ kv_mask,
                                float* __restrict__ ws)
{
    const int z  = blockIdx.z;
    const float* X   = (z==0)? query : (z==1)? key : value;
    const float* W   = (z==0)? Wq    : (z==1)? Wk  : Wv;
    const float* bia = (z==0)? bq    : (z==1)? bk  : bv;
    const u8* pm     = (z==0)? q_mask : kv_mask;
    float* out = ws + (size_t)z * (size_t)(BH*SS*DHH);

    const int h  = blockIdx.x;      // 64-wide n-tile == one head
    const int e0 = h*64;
    const int m0 = blockIdx.y*64;
    const int t  = threadIdx.x;
    const int tm = t>>4, tn = t&15;
    const int lr = t>>2, lc = (t&3)*4;

    __shared__ float As[16][68];
    __shared__ float Bs[16][68];

    float acc[4][4];
    #pragma unroll
    for (int i=0;i<4;++i)
        #pragma unroll
        for (int j=0;j<4;++j) acc[i][j]=0.f;

    for (int k0=0; k0<DD; k0+=16) {
        float4 a = ld4(&X[(size_t)(m0+lr)*DD + k0 + lc]);
        float4 w = ld4(&W[(size_t)(e0+lr)*DD + k0 + lc]);
        As[lc+0][lr]=a.x; As[lc+1][lr]=a.y; As[lc+2][lr]=a.z; As[lc+3][lr]=a.w;
        Bs[lc+0][lr]=w.x; Bs[lc+1][lr]=w.y; Bs[lc+2][lr]=w.z; Bs[lc+3][lr]=w.w;
        __syncthreads();
        #pragma unroll
        for (int kk=0; kk<16; ++kk) {
            float4 a4 = ld4(&As[kk][tm*4]);
            float4 b4 = ld4(&Bs[kk][tn*4]);
            float ar[4]={a4.x,a4.y,a4.z,a4.w};
            float br[4]={b4.x,b4.y,b4.z,b4.w};
            #pragma unroll
            for (int i=0;i<4;++i)
                #pragma unroll
                for (int j=0;j<4;++j) acc[i][j] = fmaf(ar[i],br[j],acc[i][j]);
        }
        __syncthreads();
    }
    const float scale = (z==0)? 0.125f : 1.0f;
    float bb4[4] = {bia[e0+tn*4+0],bia[e0+tn*4+1],bia[e0+tn*4+2],bia[e0+tn*4+3]};
    #pragma unroll
    for (int i=0;i<4;++i) {
        int m = m0 + tm*4 + i;
        int b = m >> 11;            // /SS
        int s = m & (SS-1);
        float msk = (pm[m]!=0) ? 0.f : 1.f;
        float4 o = make_float4((acc[i][0]+bb4[0])*scale*msk,
                               (acc[i][1]+bb4[1])*scale*msk,
                               (acc[i][2]+bb4[2])*scale*msk,
                               (acc[i][3]+bb4[3])*scale*msk);
        st4(&out[(((size_t)b*HH+h)*SS + s)*DHH + tn*4], o);
    }
}

// ---------------- K2: scores = qs.k + qs.wk_emb[pos], mask -> -inf ----------
// one block per (bh, q-tile); loops over v-tiles; zero-fills causal upper tiles
__launch_bounds__(256)
__global__ void scores_kernel(const float* __restrict__ ws,
                              const float* __restrict__ wk_emb,
                              const u8* __restrict__ kv_mask,
                              const int* __restrict__ use_sub_p,
                              float* __restrict__ attn)
{
    const int qt = blockIdx.x, bh = blockIdx.y;
    const int b  = bh >> 4;
    const int use_sub = *use_sub_p;
    const int t  = threadIdx.x;
    const int tq = t>>4, tv = t&15;

    __shared__ float qs_s[DHH][68];   // [d][q]
    __shared__ float ks_s[DHH][68];   // [d][v]   (first used as wk_emb scratch)
    __shared__ float qw_s[64][NR+1];  // [q][p]

    const float* qg = ws + ((size_t)bh*SS + (size_t)qt*64)*DHH;
    // stage q tile (transposed)
    #pragma unroll
    for (int i=0;i<4;++i){
        int r = (t>>4) + 16*i;
        float4 x = ld4(&qg[(size_t)r*DHH + (t&15)*4]);
        int c = (t&15)*4;
        qs_s[c+0][r]=x.x; qs_s[c+1][r]=x.y; qs_s[c+2][r]=x.z; qs_s[c+3][r]=x.w;
    }
    // stage wk_emb flat into ks_s storage
    float* wkf = &ks_s[0][0];
    for (int idx=t; idx < (NR*DHH)/4; idx += 256)
        ((float4*)wkf)[idx] = ((const float4*)wk_emb)[idx];
    __syncthreads();
    // qw[q][p] = sum_d qs[q][d]*wk_emb[p][d]
    for (int idx=t; idx < 64*NR; idx += 256) {
        int q = idx & 63, p = idx >> 6;
        float s = 0.f;
        #pragma unroll 8
        for (int d=0; d<DHH; ++d) s = fmaf(qs_s[d][q], wkf[p*DHH+d], s);
        qw_s[q][p] = s;
    }
    __syncthreads();

    const float* kg = ws + (size_t)(BH*SS*DHH) + (size_t)bh*SS*DHH;
    const int vtmax = use_sub ? qt : (NT-1);
    for (int vt=0; vt<=vtmax; ++vt) {
        #pragma unroll
        for (int i=0;i<4;++i){
            int r = (t>>4) + 16*i;
            float4 x = ld4(&kg[(size_t)(vt*64+r)*DHH + (t&15)*4]);
            int c = (t&15)*4;
            ks_s[c+0][r]=x.x; ks_s[c+1][r]=x.y; ks_s[c+2][r]=x.z; ks_s[c+3][r]=x.w;
        }
        __syncthreads();
        float acc[4][4];
        #pragma unroll
        for (int i=0;i<4;++i)
            #pragma unroll
            for (int j=0;j<4;++j) acc[i][j]=0.f;
        #pragma unroll 8
        for (int kk=0; kk<DHH; ++kk) {
            float4 a4 = ld4(&qs_s[kk][tq*4]);
            float4 b4 = ld4(&ks_s[kk][tv*4]);
            float ar[4]={a4.x,a4.y,a4.z,a4.w};
            float br[4]={b4.x,b4.y,b4.z,b4.w};
            #pragma unroll
            for (int i=0;i<4;++i)
                #pragma unroll
                for (int j=0;j<4;++j) acc[i][j] = fmaf(ar[i],br[j],acc[i][j]);
        }
        #pragma unroll
        for (int i=0;i<4;++i) {
            int qi = qt*64 + tq*4 + i;
            float o[4];
            #pragma unroll
            for (int j=0;j<4;++j) {
                int vi = vt*64 + tv*4 + j;
                int d  = vi - qi;
                d = d < -RK ? -RK : (d > RK ? RK : d);
                float sc = acc[i][j] + qw_s[tq*4+i][d+RK];
                bool msk = use_sub ? (vi > qi) : (kv_mask[b*SS + vi] != 0);
                o[j] = msk ? -INFINITY : sc;
            }
            st4(&attn[((size_t)bh*SS + qi)*SS + (size_t)vt*64 + tv*4],
                make_float4(o[0],o[1],o[2],o[3]));
        }
        __syncthreads();
    }
    if (use_sub) {  // zero-fill strictly-upper tiles (attn == 0 there)
        const int zc0 = (qt+1)*64;
        const float4 z4 = make_float4(0.f,0.f,0.f,0.f);
        for (int r=0; r<64; ++r) {
            float* rowp = &attn[((size_t)bh*SS + (size_t)qt*64 + r)*SS];
            for (int c = zc0 + t*4; c < SS; c += 1024) st4(&rowp[c], z4);
        }
    }
}

// ---------------- K3: per-row max & 1/sum(exp) ----------------
__launch_bounds__(256)
__global__ void rowstat_kernel(const float* __restrict__ attn,
                               const int* __restrict__ use_sub_p,
                               float* __restrict__ stats)
{
    const int use_sub = *use_sub_p;
    const int t = threadIdx.x;
    const int w = t>>6, lane = t&63;
    const int ridx = blockIdx.x*4 + w;         // over BH*SS rows
    const int q = ridx & (SS-1);
    const float* row = attn + (size_t)ridx * SS;
    const int vmax = use_sub ? q : (SS-1);

    float4 vals[8];
    float mx = -INFINITY;
    #pragma unroll
    for (int it=0; it<8; ++it) {
        int c = it*256 + lane*4;
        float4 x;
        if (c <= vmax) {
            x = ld4(&row[c]);
            if (c+1 > vmax) x.y = -INFINITY;
            if (c+2 > vmax) x.z = -INFINITY;
            if (c+3 > vmax) x.w = -INFINITY;
        } else { x.x=-INFINITY; x.y=-INFINITY; x.z=-INFINITY; x.w=-INFINITY; }
        vals[it] = x;
        mx = fmaxf(mx, fmaxf(fmaxf(x.x,x.y), fmaxf(x.z,x.w)));
    }
    #pragma unroll
    for (int off=1; off<64; off<<=1) mx = fmaxf(mx, __shfl_xor(mx, off));
    float sm = 0.f;
    #pragma unroll
    for (int it=0; it<8; ++it) {
        sm += expf(vals[it].x - mx) + expf(vals[it].y - mx)
            + expf(vals[it].z - mx) + expf(vals[it].w - mx);
    }
    #pragma unroll
    for (int off=1; off<64; off<<=1) sm += __shfl_xor(sm, off);
    if (lane == 0) {
        stats[(size_t)ridx*2+0] = mx;
        stats[(size_t)ridx*2+1] = 1.f/sm;
    }
}

// ---------------- K4: softmax (in-place) + A@V + rel-V buckets, writes x ----
__launch_bounds__(256)
__global__ void softmax_av_kernel(float* __restrict__ ws,
                                  const float* __restrict__ wv_emb,
                                  const int* __restrict__ use_sub_p,
                                  float* __restrict__ attn)
{
    const int qt = blockIdx.x, bh = blockIdx.y;
    const int b = bh >> 4, h = bh & 15;
    const int use_sub = *use_sub_p;
    const int t = threadIdx.x;
    const int tq = t>>4, tv = t&15;

    __shared__ float vv_s[64][68];    // [v][d]; reused as reduce scratch
    __shared__ float a_s[64][68];     // [v][q]; reused as mid buckets
    __shared__ float wv_s[NR][DHH];

    const size_t NF = (size_t)BH*SS*DHH;
    const float* vg    = ws + 2*NF + (size_t)bh*SS*DHH;
    const float* stats = ws + 4*NF;
    float* xout        = ws + 3*NF;

    for (int idx=t; idx < (NR*DHH)/4; idx += 256)
        ((float4*)&wv_s[0][0])[idx] = ((const float4*)wv_emb)[idx];

    float m_i[4], invl[4];
    #pragma unroll
    for (int i=0;i<4;++i){
        size_t qi = (size_t)bh*SS + qt*64 + tq*4 + i;
        m_i[i]  = stats[qi*2+0];
        invl[i] = stats[qi*2+1];
    }
    float acc[4][4];
    #pragma unroll
    for (int i=0;i<4;++i)
        #pragma unroll
        for (int j=0;j<4;++j) acc[i][j]=0.f;
    float pb0[4]={0.f,0.f,0.f,0.f}, pb32[4]={0.f,0.f,0.f,0.f};

    const int vtmax = use_sub ? qt : (NT-1);
    for (int vt=0; vt<=vtmax; ++vt) {
        #pragma unroll
        for (int i=0;i<4;++i){
            int r = (t>>4) + 16*i;
            float4 x = ld4(&vg[(size_t)(vt*64+r)*DHH + (t&15)*4]);
            st4(&vv_s[r][(t&15)*4], x);
        }
        #pragma unroll
        for (int i=0;i<4;++i){
            int qi = qt*64 + tq*4 + i;
            float* rowp = &attn[((size_t)bh*SS + qi)*SS];
            float4 sv = ld4(&rowp[(size_t)vt*64 + tv*4]);
            float a0 = expf(sv.x - m_i[i])*invl[i];
            float a1 = expf(sv.y - m_i[i])*invl[i];
            float a2 = expf(sv.z - m_i[i])*invl[i];
            float a3 = expf(sv.w - m_i[i])*invl[i];
            st4(&rowp[(size_t)vt*64 + tv*4], make_float4(a0,a1,a2,a3));
            a_s[tv*4+0][tq*4+i]=a0; a_s[tv*4+1][tq*4+i]=a1;
            a_s[tv*4+2][tq*4+i]=a2; a_s[tv*4+3][tq*4+i]=a3;
            int v0 = vt*64 + tv*4;
            if (v0+0 <= qi-RK) pb0[i]+=a0; else if (v0+0 >= qi+RK) pb32[i]+=a0;
            if (v0+1 <= qi-RK) pb0[i]+=a1; else if (v0+1 >= qi+RK) pb32[i]+=a1;
            if (v0+2 <= qi-RK) pb0[i]+=a2; else if (v0+2 >= qi+RK) pb32[i]+=a2;
            if (v0+3 <= qi-RK) pb0[i]+=a3; else if (v0+3 >= qi+RK) pb32[i]+=a3;
        }
        __syncthreads();
        #pragma unroll 8
        for (int kk=0; kk<64; ++kk) {
            float4 a4 = ld4(&a_s[kk][tq*4]);
            float4 v4 = ld4(&vv_s[kk][tv*4]);
            float ar[4]={a4.x,a4.y,a4.z,a4.w};
            float vr[4]={v4.x,v4.y,v4.z,v4.w};
            #pragma unroll
            for (int i=0;i<4;++i)
                #pragma unroll
                for (int j=0;j<4;++j) acc[i][j] = fmaf(ar[i],vr[j],acc[i][j]);
        }
        __syncthreads();
    }

    __threadfence_block();
    __syncthreads();
    float* mid = &a_s[0][0];    // [64][34] flat
    float* red = &vv_s[0][0];   // [64][17] flat
    #pragma unroll
    for (int i=0;i<4;++i) red[(tq*4+i)*17 + tv] = pb0[i];
    __syncthreads();
    if (t < 64) { float s=0.f; for (int j=0;j<16;++j) s += red[t*17+j]; mid[t*34+0] = s; }
    __syncthreads();
    #pragma unroll
    for (int i=0;i<4;++i) red[(tq*4+i)*17 + tv] = pb32[i];
    __syncthreads();
    if (t < 64) {
        float s=0.f; for (int j=0;j<16;++j) s += red[t*17+j]; mid[t*34+32] = s;
        int qi = qt*64 + t;
        const float* rowp = &attn[((size_t)bh*SS + qi)*SS];
        for (int p=1; p<32; ++p) {
            int v = qi - RK + p;
            mid[t*34+p] = (v >= 0 && v < SS) ? rowp[v] : 0.f;
        }
    }
    __syncthreads();
    #pragma unroll 4
    for (int p=0; p<NR; ++p) {
        float4 w4 = ld4(&wv_s[p][tv*4]);
        #pragma unroll
        for (int i=0;i<4;++i) {
            float mm = mid[(tq*4+i)*34 + p];
            acc[i][0] = fmaf(mm,w4.x,acc[i][0]);
            acc[i][1] = fmaf(mm,w4.y,acc[i][1]);
            acc[i][2] = fmaf(mm,w4.z,acc[i][2]);
            acc[i][3] = fmaf(mm,w4.w,acc[i][3]);
        }
    }
    #pragma unroll
    for (int i=0;i<4;++i){
        int qi = qt*64 + tq*4 + i;
        st4(&xout[((size_t)b*SS + qi)*DD + h*DHH + tv*4],
            make_float4(acc[i][0],acc[i][1],acc[i][2],acc[i][3]));
    }
}

// ---------------- K5: output projection ----------------
__launch_bounds__(256)
__global__ void proj_out_kernel(const float* __restrict__ ws,
                                const float* __restrict__ Wo, const float* __restrict__ bo,
                                const u8* __restrict__ q_mask,
                                float* __restrict__ outp)
{
    const float* X = ws + 3*(size_t)(BH*SS*DHH);
    const int e0 = blockIdx.x*64;
    const int m0 = blockIdx.y*64;
    const int t  = threadIdx.x;
    const int tm = t>>4, tn = t&15;
    const int lr = t>>2, lc = (t&3)*4;

    __shared__ float As[16][68];
    __shared__ float Bs[16][68];

    float acc[4][4];
    #pragma unroll
    for (int i=0;i<4;++i)
        #pragma unroll
        for (int j=0;j<4;++j) acc[i][j]=0.f;

    for (int k0=0; k0<DD; k0+=16) {
        float4 a = ld4(&X[(size_t)(m0+lr)*DD + k0 + lc]);
        float4 w = ld4(&Wo[(size_t)(e0+lr)*DD + k0 + lc]);
        As[lc+0][lr]=a.x; As[lc+1][lr]=a.y; As[lc+2][lr]=a.z; As[lc+3][lr]=a.w;
        Bs[lc+0][lr]=w.x; Bs[lc+1][lr]=w.y; Bs[lc+2][lr]=w.z; Bs[lc+3][lr]=w.w;
        __syncthreads();
        #pragma unroll
        for (int kk=0; kk<16; ++kk) {
            float4 a4 = ld4(&As[kk][tm*4]);
            float4 b4 = ld4(&Bs[kk][tn*4]);
            float ar[4]={a4.x,a4.y,a4.z,a4.w};
            float br[4]={b4.x,b4.y,b4.z,b4.w};
            #pragma unroll
            for (int i=0;i<4;++i)
                #pragma unroll
                for (int j=0;j<4;++j) acc[i][j] = fmaf(ar[i],br[j],acc[i][j]);
        }
        __syncthreads();
    }
    float bb4[4] = {bo[e0+tn*4+0],bo[e0+tn*4+1],bo[e0+tn*4+2],bo[e0+tn*4+3]};
    #pragma unroll
    for (int i=0;i<4;++i) {
        int m = m0 + tm*4 + i;
        float msk = (q_mask[m]!=0) ? 0.f : 1.f;
        float4 o = make_float4((acc[i][0]+bb4[0])*msk, (acc[i][1]+bb4[1])*msk,
                               (acc[i][2]+bb4[2])*msk, (acc[i][3]+bb4[3])*msk);
        st4(&outp[(size_t)m*DD + e0 + tn*4], o);
    }
}

extern "C" void kernel_launch(void* const* d_in, const int* in_sizes, int n_in,
                              void* d_out, int out_size, void* d_ws, size_t ws_size,
                              hipStream_t stream)
{
    const float* query = (const float*)d_in[0];
    const float* key_  = (const float*)d_in[1];
    const float* value = (const float*)d_in[2];
    const u8*    q_mask  = (const u8*)d_in[3];
    const u8*    kv_mask = (const u8*)d_in[4];
    const int*   use_sub = (const int*)d_in[5];
    const float* Wq = (const float*)d_in[6];  const float* bq = (const float*)d_in[7];
    const float* Wk = (const float*)d_in[8];  const float* bk = (const float*)d_in[9];
    const float* Wv = (const float*)d_in[10]; const float* bv = (const float*)d_in[11];
    const float* Wo = (const float*)d_in[12]; const float* bo = (const float*)d_in[13];
    const float* wk_emb = (const float*)d_in[14];
    const float* wv_emb = (const float*)d_in[15];

    float* outp = (float*)d_out;
    float* attn = outp + (size_t)MT*DD;
    float* ws   = (float*)d_ws;
    float* stats = ws + 4*(size_t)(BH*SS*DHH);

    proj_qkv_kernel<<<dim3(16,64,3), 256, 0, stream>>>(
        query, key_, value, Wq, bq, Wk, bk, Wv, bv, q_mask, kv_mask, ws);
    scores_kernel<<<dim3(NT,BH), 256, 0, stream>>>(ws, wk_emb, kv_mask, use_sub, attn);
    rowstat_kernel<<<dim3(BH*SS/4), 256, 0, stream>>>(attn, use_sub, stats);
    softmax_av_kernel<<<dim3(NT,BH), 256, 0, stream>>>(ws, wv_emb, use_sub, attn);
    proj_out_kernel<<<dim3(16,64), 256, 0, stream>>>(ws, Wo, bo, q_mask, outp);
}

// Round 3
// 1531.622 us; speedup vs baseline: 1.1645x; 1.1645x over previous
//
#include <hip/hip_runtime.h>
#include <math.h>

#define BB  2
#define SS  2048
#define DD  1024
#define HH  16
#define DHH 64
#define RK  16
#define NR  33          // 2*RK+1
#define BH  (BB*HH)     // 32
#define MT  (BB*SS)     // 4096
#define NT  (SS/64)     // 32
#define NF  ((size_t)BH*SS*DHH)

typedef unsigned char u8;
typedef __attribute__((ext_vector_type(8))) short short8v;
typedef __attribute__((ext_vector_type(4))) float f32x4;

__device__ __forceinline__ float4 ld4(const float* p){ return *reinterpret_cast<const float4*>(p); }
__device__ __forceinline__ void st4(float* p, float4 v){ *reinterpret_cast<float4*>(p) = v; }

__device__ __forceinline__ unsigned short f2bf(float f){
    union { float f; unsigned u; } v; v.f = f;
    unsigned r = v.u + 0x7fffu + ((v.u >> 16) & 1u);   // RNE
    return (unsigned short)(r >> 16);
}
__device__ __forceinline__ float bf2f(unsigned short h){
    union { unsigned u; float f; } v; v.u = ((unsigned)h) << 16;
    return v.f;
}

// ======================================================================
// bf16-split MFMA GEMM core: C[m][e] = sum_d X[m,d] * W[e,d]
// 128x128 tile, BK=64, 4 waves (2x2), each wave 64x64 via 4x4 frags of
// 16x16x32. Split A=Ah+Al, B=Bh+Bl; compute AhBh + AhBl + AlBh.
// LDS holds fragment-linear units: idx=((strip*2+c)*4+i)*64+lane, 16B each.
// ======================================================================
__device__ __forceinline__ void gemm_split_core(
    const float* __restrict__ X, const float* __restrict__ W,
    const float* __restrict__ bias, const u8* __restrict__ rmask,
    float* __restrict__ out, float scale, int qkv_mode, int m0, int n0)
{
    __shared__ short8v buf[4096];   // 64 KiB: [Ah|Al|Bh|Bl] x 1024 units
    const int t    = threadIdx.x;
    const int lane = t & 63;
    const int w    = t >> 6;
    const int wm   = w >> 1, wn = w & 1;

    f32x4 acc[4][4];
    #pragma unroll
    for (int i=0;i<4;++i)
        #pragma unroll
        for (int j=0;j<4;++j) acc[i][j] = (f32x4){0.f,0.f,0.f,0.f};

    for (int k0 = 0; k0 < DD; k0 += 64) {
        __syncthreads();
        #pragma unroll
        for (int s = 0; s < 4; ++s) {
            const int u  = t + 256*s;          // unit id 0..1023
            const int ri = u >> 3, kg = u & 7; // row in tile, k-group of 8
            const int iu = (ri >> 4) & 3, ll = ri & 15;
            const int cu = kg >> 2,      lh = kg & 3;
            const int idx = (((ri >> 6)*2 + cu)*4 + iu)*64 + lh*16 + ll;
            {
                const float* gp = &X[(size_t)(m0 + ri)*DD + k0 + kg*8];
                float4 x0 = ld4(gp), x1 = ld4(gp+4);
                float xs[8] = {x0.x,x0.y,x0.z,x0.w,x1.x,x1.y,x1.z,x1.w};
                short8v h, l;
                #pragma unroll
                for (int e = 0; e < 8; ++e) {
                    unsigned short hu = f2bf(xs[e]);
                    h[e] = (short)hu;
                    l[e] = (short)f2bf(xs[e] - bf2f(hu));
                }
                buf[idx] = h; buf[1024 + idx] = l;
            }
            {
                const float* gp = &W[(size_t)(n0 + ri)*DD + k0 + kg*8];
                float4 x0 = ld4(gp), x1 = ld4(gp+4);
                float xs[8] = {x0.x,x0.y,x0.z,x0.w,x1.x,x1.y,x1.z,x1.w};
                short8v h, l;
                #pragma unroll
                for (int e = 0; e < 8; ++e) {
                    unsigned short hu = f2bf(xs[e]);
                    h[e] = (short)hu;
                    l[e] = (short)f2bf(xs[e] - bf2f(hu));
                }
                buf[2048 + idx] = h; buf[3072 + idx] = l;
            }
        }
        __syncthreads();
        #pragma unroll
        for (int c = 0; c < 2; ++c) {
            short8v ah[4], al[4], bh[4], bl[4];
            const int ab = ((wm*2 + c)*4)*64 + lane;
            const int bb = ((wn*2 + c)*4)*64 + lane;
            #pragma unroll
            for (int i = 0; i < 4; ++i) {
                ah[i] = buf[       ab + i*64];
                al[i] = buf[1024 + ab + i*64];
                bh[i] = buf[2048 + bb + i*64];
                bl[i] = buf[3072 + bb + i*64];
            }
            #pragma unroll
            for (int i = 0; i < 4; ++i)
                #pragma unroll
                for (int j = 0; j < 4; ++j) {
                    acc[i][j] = __builtin_amdgcn_mfma_f32_16x16x32_bf16(ah[i], bh[j], acc[i][j], 0,0,0);
                    acc[i][j] = __builtin_amdgcn_mfma_f32_16x16x32_bf16(ah[i], bl[j], acc[i][j], 0,0,0);
                    acc[i][j] = __builtin_amdgcn_mfma_f32_16x16x32_bf16(al[i], bh[j], acc[i][j], 0,0,0);
                }
        }
    }

    // epilogue: C/D layout col=lane&15, row=(lane>>4)*4+r  [m89/m91]
    const int colb = n0 + wn*64 + (lane & 15);
    const int rowb = m0 + wm*64 + ((lane >> 4) << 2);
    #pragma unroll
    for (int j = 0; j < 4; ++j) {
        const int e  = colb + j*16;
        const float be = bias[e];
        const int hh = e >> 6, dh = e & 63;
        #pragma unroll
        for (int i = 0; i < 4; ++i) {
            #pragma unroll
            for (int r = 0; r < 4; ++r) {
                const int m = rowb + i*16 + r;
                float v = (acc[i][j][r] + be) * scale;
                if (rmask[m]) v = 0.f;
                if (qkv_mode) {
                    const int b = m >> 11, s = m & (SS-1);
                    out[(((size_t)b*HH + hh)*SS + s)*DHH + dh] = v;
                } else {
                    out[(size_t)m*DD + e] = v;
                }
            }
        }
    }
}

__global__ __launch_bounds__(256,2)
void proj_qkv_mfma(const float* __restrict__ query,
                   const float* __restrict__ key,
                   const float* __restrict__ value,
                   const float* __restrict__ Wq, const float* __restrict__ bq,
                   const float* __restrict__ Wk, const float* __restrict__ bk,
                   const float* __restrict__ Wv, const float* __restrict__ bv,
                   const u8* __restrict__ q_mask, const u8* __restrict__ kv_mask,
                   float* __restrict__ ws)
{
    const int z = blockIdx.z;
    const float* X   = (z==0)? query : (z==1)? key : value;
    const float* W   = (z==0)? Wq    : (z==1)? Wk  : Wv;
    const float* bia = (z==0)? bq    : (z==1)? bk  : bv;
    const u8* pm     = (z==0)? q_mask : kv_mask;
    float* out = ws + (size_t)z * NF;
    const float scale = (z==0)? 0.125f : 1.0f;
    gemm_split_core(X, W, bia, pm, out, scale, 1, blockIdx.y*128, blockIdx.x*128);
}

__global__ __launch_bounds__(256,2)
void proj_out_mfma(const float* __restrict__ ws,
                   const float* __restrict__ Wo, const float* __restrict__ bo,
                   const u8* __restrict__ q_mask,
                   float* __restrict__ outp)
{
    gemm_split_core(ws + 3*NF, Wo, bo, q_mask, outp, 1.0f, 0,
                    blockIdx.y*128, blockIdx.x*128);
}

// ---------------- K2: scores = qs.k + qs.wk_emb[pos], mask -> -inf ----------
__launch_bounds__(256)
__global__ void scores_kernel(const float* __restrict__ ws,
                              const float* __restrict__ wk_emb,
                              const u8* __restrict__ kv_mask,
                              const int* __restrict__ use_sub_p,
                              float* __restrict__ attn)
{
    const int qt = blockIdx.x, bh = blockIdx.y;
    const int b  = bh >> 4;
    const int use_sub = *use_sub_p;
    const int t  = threadIdx.x;
    const int tq = t>>4, tv = t&15;

    __shared__ float qs_s[DHH][68];   // [d][q]
    __shared__ float ks_s[DHH][68];   // [d][v]   (first used as wk_emb scratch)
    __shared__ float qw_s[64][NR+1];  // [q][p]

    const float* qg = ws + ((size_t)bh*SS + (size_t)qt*64)*DHH;
    #pragma unroll
    for (int i=0;i<4;++i){
        int r = (t>>4) + 16*i;
        float4 x = ld4(&qg[(size_t)r*DHH + (t&15)*4]);
        int c = (t&15)*4;
        qs_s[c+0][r]=x.x; qs_s[c+1][r]=x.y; qs_s[c+2][r]=x.z; qs_s[c+3][r]=x.w;
    }
    float* wkf = &ks_s[0][0];
    for (int idx=t; idx < (NR*DHH)/4; idx += 256)
        ((float4*)wkf)[idx] = ((const float4*)wk_emb)[idx];
    __syncthreads();
    for (int idx=t; idx < 64*NR; idx += 256) {
        int q = idx & 63, p = idx >> 6;
        float s = 0.f;
        #pragma unroll 8
        for (int d=0; d<DHH; ++d) s = fmaf(qs_s[d][q], wkf[p*DHH+d], s);
        qw_s[q][p] = s;
    }
    __syncthreads();

    const float* kg = ws + NF + (size_t)bh*SS*DHH;
    const int vtmax = use_sub ? qt : (NT-1);
    for (int vt=0; vt<=vtmax; ++vt) {
        #pragma unroll
        for (int i=0;i<4;++i){
            int r = (t>>4) + 16*i;
            float4 x = ld4(&kg[(size_t)(vt*64+r)*DHH + (t&15)*4]);
            int c = (t&15)*4;
            ks_s[c+0][r]=x.x; ks_s[c+1][r]=x.y; ks_s[c+2][r]=x.z; ks_s[c+3][r]=x.w;
        }
        __syncthreads();
        float acc[4][4];
        #pragma unroll
        for (int i=0;i<4;++i)
            #pragma unroll
            for (int j=0;j<4;++j) acc[i][j]=0.f;
        #pragma unroll 8
        for (int kk=0; kk<DHH; ++kk) {
            float4 a4 = ld4(&qs_s[kk][tq*4]);
            float4 b4 = ld4(&ks_s[kk][tv*4]);
            float ar[4]={a4.x,a4.y,a4.z,a4.w};
            float br[4]={b4.x,b4.y,b4.z,b4.w};
            #pragma unroll
            for (int i=0;i<4;++i)
                #pragma unroll
                for (int j=0;j<4;++j) acc[i][j] = fmaf(ar[i],br[j],acc[i][j]);
        }
        #pragma unroll
        for (int i=0;i<4;++i) {
            int qi = qt*64 + tq*4 + i;
            float o[4];
            #pragma unroll
            for (int j=0;j<4;++j) {
                int vi = vt*64 + tv*4 + j;
                int d  = vi - qi;
                d = d < -RK ? -RK : (d > RK ? RK : d);
                float sc = acc[i][j] + qw_s[tq*4+i][d+RK];
                bool msk = use_sub ? (vi > qi) : (kv_mask[b*SS + vi] != 0);
                o[j] = msk ? -INFINITY : sc;
            }
            st4(&attn[((size_t)bh*SS + qi)*SS + (size_t)vt*64 + tv*4],
                make_float4(o[0],o[1],o[2],o[3]));
        }
        __syncthreads();
    }
    if (use_sub) {
        const int zc0 = (qt+1)*64;
        const float4 z4 = make_float4(0.f,0.f,0.f,0.f);
        for (int r=0; r<64; ++r) {
            float* rowp = &attn[((size_t)bh*SS + (size_t)qt*64 + r)*SS];
            for (int c = zc0 + t*4; c < SS; c += 1024) st4(&rowp[c], z4);
        }
    }
}

// ---------------- K3: per-row max & 1/sum(exp) ----------------
__launch_bounds__(256)
__global__ void rowstat_kernel(const float* __restrict__ attn,
                               const int* __restrict__ use_sub_p,
                               float* __restrict__ stats)
{
    const int use_sub = *use_sub_p;
    const int t = threadIdx.x;
    const int w = t>>6, lane = t&63;
    const int ridx = blockIdx.x*4 + w;
    const int q = ridx & (SS-1);
    const float* row = attn + (size_t)ridx * SS;
    const int vmax = use_sub ? q : (SS-1);

    float4 vals[8];
    float mx = -INFINITY;
    #pragma unroll
    for (int it=0; it<8; ++it) {
        int c = it*256 + lane*4;
        float4 x;
        if (c <= vmax) {
            x = ld4(&row[c]);
            if (c+1 > vmax) x.y = -INFINITY;
            if (c+2 > vmax) x.z = -INFINITY;
            if (c+3 > vmax) x.w = -INFINITY;
        } else { x.x=-INFINITY; x.y=-INFINITY; x.z=-INFINITY; x.w=-INFINITY; }
        vals[it] = x;
        mx = fmaxf(mx, fmaxf(fmaxf(x.x,x.y), fmaxf(x.z,x.w)));
    }
    #pragma unroll
    for (int off=1; off<64; off<<=1) mx = fmaxf(mx, __shfl_xor(mx, off));
    float sm = 0.f;
    #pragma unroll
    for (int it=0; it<8; ++it) {
        sm += expf(vals[it].x - mx) + expf(vals[it].y - mx)
            + expf(vals[it].z - mx) + expf(vals[it].w - mx);
    }
    #pragma unroll
    for (int off=1; off<64; off<<=1) sm += __shfl_xor(sm, off);
    if (lane == 0) {
        stats[(size_t)ridx*2+0] = mx;
        stats[(size_t)ridx*2+1] = 1.f/sm;
    }
}

// ---------------- K4: softmax (in-place) + A@V + rel-V buckets, writes x ----
__launch_bounds__(256)
__global__ void softmax_av_kernel(float* __restrict__ ws,
                                  const float* __restrict__ wv_emb,
                                  const int* __restrict__ use_sub_p,
                                  float* __restrict__ attn)
{
    const int qt = blockIdx.x, bh = blockIdx.y;
    const int b = bh >> 4, h = bh & 15;
    const int use_sub = *use_sub_p;
    const int t = threadIdx.x;
    const int tq = t>>4, tv = t&15;

    __shared__ float vv_s[64][68];
    __shared__ float a_s[64][68];
    __shared__ float wv_s[NR][DHH];

    const float* vg    = ws + 2*NF + (size_t)bh*SS*DHH;
    const float* stats = ws + 4*NF;
    float* xout        = ws + 3*NF;

    for (int idx=t; idx < (NR*DHH)/4; idx += 256)
        ((float4*)&wv_s[0][0])[idx] = ((const float4*)wv_emb)[idx];

    float m_i[4], invl[4];
    #pragma unroll
    for (int i=0;i<4;++i){
        size_t qi = (size_t)bh*SS + qt*64 + tq*4 + i;
        m_i[i]  = stats[qi*2+0];
        invl[i] = stats[qi*2+1];
    }
    float acc[4][4];
    #pragma unroll
    for (int i=0;i<4;++i)
        #pragma unroll
        for (int j=0;j<4;++j) acc[i][j]=0.f;
    float pb0[4]={0.f,0.f,0.f,0.f}, pb32[4]={0.f,0.f,0.f,0.f};

    const int vtmax = use_sub ? qt : (NT-1);
    for (int vt=0; vt<=vtmax; ++vt) {
        #pragma unroll
        for (int i=0;i<4;++i){
            int r = (t>>4) + 16*i;
            float4 x = ld4(&vg[(size_t)(vt*64+r)*DHH + (t&15)*4]);
            st4(&vv_s[r][(t&15)*4], x);
        }
        #pragma unroll
        for (int i=0;i<4;++i){
            int qi = qt*64 + tq*4 + i;
            float* rowp = &attn[((size_t)bh*SS + qi)*SS];
            float4 sv = ld4(&rowp[(size_t)vt*64 + tv*4]);
            float a0 = expf(sv.x - m_i[i])*invl[i];
            float a1 = expf(sv.y - m_i[i])*invl[i];
            float a2 = expf(sv.z - m_i[i])*invl[i];
            float a3 = expf(sv.w - m_i[i])*invl[i];
            st4(&rowp[(size_t)vt*64 + tv*4], make_float4(a0,a1,a2,a3));
            a_s[tv*4+0][tq*4+i]=a0; a_s[tv*4+1][tq*4+i]=a1;
            a_s[tv*4+2][tq*4+i]=a2; a_s[tv*4+3][tq*4+i]=a3;
            int v0 = vt*64 + tv*4;
            if (v0+0 <= qi-RK) pb0[i]+=a0; else if (v0+0 >= qi+RK) pb32[i]+=a0;
            if (v0+1 <= qi-RK) pb0[i]+=a1; else if (v0+1 >= qi+RK) pb32[i]+=a1;
            if (v0+2 <= qi-RK) pb0[i]+=a2; else if (v0+2 >= qi+RK) pb32[i]+=a2;
            if (v0+3 <= qi-RK) pb0[i]+=a3; else if (v0+3 >= qi+RK) pb32[i]+=a3;
        }
        __syncthreads();
        #pragma unroll 8
        for (int kk=0; kk<64; ++kk) {
            float4 a4 = ld4(&a_s[kk][tq*4]);
            float4 v4 = ld4(&vv_s[kk][tv*4]);
            float ar[4]={a4.x,a4.y,a4.z,a4.w};
            float vr[4]={v4.x,v4.y,v4.z,v4.w};
            #pragma unroll
            for (int i=0;i<4;++i)
                #pragma unroll
                for (int j=0;j<4;++j) acc[i][j] = fmaf(ar[i],vr[j],acc[i][j]);
        }
        __syncthreads();
    }

    __threadfence_block();
    __syncthreads();
    float* mid = &a_s[0][0];
    float* red = &vv_s[0][0];
    #pragma unroll
    for (int i=0;i<4;++i) red[(tq*4+i)*17 + tv] = pb0[i];
    __syncthreads();
    if (t < 64) { float s=0.f; for (int j=0;j<16;++j) s += red[t*17+j]; mid[t*34+0] = s; }
    __syncthreads();
    #pragma unroll
    for (int i=0;i<4;++i) red[(tq*4+i)*17 + tv] = pb32[i];
    __syncthreads();
    if (t < 64) {
        float s=0.f; for (int j=0;j<16;++j) s += red[t*17+j]; mid[t*34+32] = s;
        int qi = qt*64 + t;
        const float* rowp = &attn[((size_t)bh*SS + qi)*SS];
        for (int p=1; p<32; ++p) {
            int v = qi - RK + p;
            mid[t*34+p] = (v >= 0 && v < SS) ? rowp[v] : 0.f;
        }
    }
    __syncthreads();
    #pragma unroll 4
    for (int p=0; p<NR; ++p) {
        float4 w4 = ld4(&wv_s[p][tv*4]);
        #pragma unroll
        for (int i=0;i<4;++i) {
            float mm = mid[(tq*4+i)*34 + p];
            acc[i][0] = fmaf(mm,w4.x,acc[i][0]);
            acc[i][1] = fmaf(mm,w4.y,acc[i][1]);
            acc[i][2] = fmaf(mm,w4.z,acc[i][2]);
            acc[i][3] = fmaf(mm,w4.w,acc[i][3]);
        }
    }
    #pragma unroll
    for (int i=0;i<4;++i){
        int qi = qt*64 + tq*4 + i;
        st4(&xout[((size_t)b*SS + qi)*DD + h*DHH + tv*4],
            make_float4(acc[i][0],acc[i][1],acc[i][2],acc[i][3]));
    }
}

extern "C" void kernel_launch(void* const* d_in, const int* in_sizes, int n_in,
                              void* d_out, int out_size, void* d_ws, size_t ws_size,
                              hipStream_t stream)
{
    const float* query = (const float*)d_in[0];
    const float* key_  = (const float*)d_in[1];
    const float* value = (const float*)d_in[2];
    const u8*    q_mask  = (const u8*)d_in[3];
    const u8*    kv_mask = (const u8*)d_in[4];
    const int*   use_sub = (const int*)d_in[5];
    const float* Wq = (const float*)d_in[6];  const float* bq = (const float*)d_in[7];
    const float* Wk = (const float*)d_in[8];  const float* bk = (const float*)d_in[9];
    const float* Wv = (const float*)d_in[10]; const float* bv = (const float*)d_in[11];
    const float* Wo = (const float*)d_in[12]; const float* bo = (const float*)d_in[13];
    const float* wk_emb = (const float*)d_in[14];
    const float* wv_emb = (const float*)d_in[15];

    float* outp = (float*)d_out;
    float* attn = outp + (size_t)MT*DD;
    float* ws   = (float*)d_ws;
    float* stats = ws + 4*NF;

    proj_qkv_mfma<<<dim3(8,32,3), 256, 0, stream>>>(
        query, key_, value, Wq, bq, Wk, bk, Wv, bv, q_mask, kv_mask, ws);
    scores_kernel<<<dim3(NT,BH), 256, 0, stream>>>(ws, wk_emb, kv_mask, use_sub, attn);
    rowstat_kernel<<<dim3(BH*SS/4), 256, 0, stream>>>(attn, use_sub, stats);
    softmax_av_kernel<<<dim3(NT,BH), 256, 0, stream>>>(ws, wv_emb, use_sub, attn);
    proj_out_mfma<<<dim3(8,32), 256, 0, stream>>>(ws, Wo, bo, q_mask, outp);
}

// Round 4
// 1419.187 us; speedup vs baseline: 1.2567x; 1.0792x over previous
//
#include <hip/hip_runtime.h>
#include <math.h>

#define BB  2
#define SS  2048
#define DD  1024
#define HH  16
#define DHH 64
#define RK  16
#define NR  33          // 2*RK+1
#define BH  (BB*HH)     // 32
#define MT  (BB*SS)     // 4096
#define NT  (SS/64)     // 32
#define NF  ((size_t)BH*SS*DHH)   // 4,194,304 elements

typedef unsigned char u8;
typedef unsigned short u16;
typedef __attribute__((ext_vector_type(8))) short short8v;
typedef __attribute__((ext_vector_type(4))) float f32x4;

__device__ __forceinline__ float4 ld4(const float* p){ return *reinterpret_cast<const float4*>(p); }
__device__ __forceinline__ void st4(float* p, float4 v){ *reinterpret_cast<float4*>(p) = v; }

__device__ __forceinline__ u16 f2bf(float f){
    union { float f; unsigned u; } v; v.f = f;
    unsigned r = v.u + 0x7fffu + ((v.u >> 16) & 1u);   // RNE
    return (u16)(r >> 16);
}
__device__ __forceinline__ float bf2f(u16 h){
    union { unsigned u; float f; } v; v.u = ((unsigned)h) << 16;
    return v.f;
}

// ======================================================================
// bf16-split MFMA GEMM core: C[m][e] = sum_d X[m,d] * W[e,d]
// 128x128 tile, BK=64, 4 waves (2x2). Epilogue modes:
//   emode 0: fp32 out[m][DD]
//   emode 1: bf16 hi/lo pairs, layout [bh][s][64]   (Q, K)
//   emode 2: bf16 hi/lo pairs, layout [bh][d][2048] (V transposed)
// ======================================================================
__device__ __forceinline__ void gemm_core(
    const float* __restrict__ X, const float* __restrict__ W,
    const float* __restrict__ bias, const u8* __restrict__ rmask,
    float scale, int m0, int n0, int emode,
    float* __restrict__ outf, u16* __restrict__ out_hi, u16* __restrict__ out_lo)
{
    __shared__ short8v buf[4096];   // 64 KiB: [Ah|Al|Bh|Bl] x 1024 units
    const int t    = threadIdx.x;
    const int lane = t & 63;
    const int w    = t >> 6;
    const int wm   = w >> 1, wn = w & 1;

    f32x4 acc[4][4];
    #pragma unroll
    for (int i=0;i<4;++i)
        #pragma unroll
        for (int j=0;j<4;++j) acc[i][j] = (f32x4){0.f,0.f,0.f,0.f};

    for (int k0 = 0; k0 < DD; k0 += 64) {
        __syncthreads();
        #pragma unroll
        for (int s = 0; s < 4; ++s) {
            const int u  = t + 256*s;
            const int ri = u >> 3, kg = u & 7;
            const int iu = (ri >> 4) & 3, llx = ri & 15;
            const int cu = kg >> 2,       lh = kg & 3;
            const int idx = (((ri >> 6)*2 + cu)*4 + iu)*64 + lh*16 + llx;
            {
                const float* gp = &X[(size_t)(m0 + ri)*DD + k0 + kg*8];
                float4 x0 = ld4(gp), x1 = ld4(gp+4);
                float xs[8] = {x0.x,x0.y,x0.z,x0.w,x1.x,x1.y,x1.z,x1.w};
                short8v h, l;
                #pragma unroll
                for (int e = 0; e < 8; ++e) {
                    u16 hu = f2bf(xs[e]);
                    h[e] = (short)hu;
                    l[e] = (short)f2bf(xs[e] - bf2f(hu));
                }
                buf[idx] = h; buf[1024 + idx] = l;
            }
            {
                const float* gp = &W[(size_t)(n0 + ri)*DD + k0 + kg*8];
                float4 x0 = ld4(gp), x1 = ld4(gp+4);
                float xs[8] = {x0.x,x0.y,x0.z,x0.w,x1.x,x1.y,x1.z,x1.w};
                short8v h, l;
                #pragma unroll
                for (int e = 0; e < 8; ++e) {
                    u16 hu = f2bf(xs[e]);
                    h[e] = (short)hu;
                    l[e] = (short)f2bf(xs[e] - bf2f(hu));
                }
                buf[2048 + idx] = h; buf[3072 + idx] = l;
            }
        }
        __syncthreads();
        #pragma unroll
        for (int c = 0; c < 2; ++c) {
            short8v ah[4], al[4], bh2[4], bl[4];
            const int ab = ((wm*2 + c)*4)*64 + lane;
            const int bb = ((wn*2 + c)*4)*64 + lane;
            #pragma unroll
            for (int i = 0; i < 4; ++i) {
                ah[i]  = buf[       ab + i*64];
                al[i]  = buf[1024 + ab + i*64];
                bh2[i] = buf[2048 + bb + i*64];
                bl[i]  = buf[3072 + bb + i*64];
            }
            #pragma unroll
            for (int i = 0; i < 4; ++i)
                #pragma unroll
                for (int j = 0; j < 4; ++j) {
                    acc[i][j] = __builtin_amdgcn_mfma_f32_16x16x32_bf16(ah[i], bh2[j], acc[i][j], 0,0,0);
                    acc[i][j] = __builtin_amdgcn_mfma_f32_16x16x32_bf16(ah[i], bl[j],  acc[i][j], 0,0,0);
                    acc[i][j] = __builtin_amdgcn_mfma_f32_16x16x32_bf16(al[i], bh2[j], acc[i][j], 0,0,0);
                }
        }
    }

    // epilogue: C/D layout col=lane&15, row=(lane>>4)*4+r
    const int colb = n0 + wn*64 + (lane & 15);
    const int rowb = m0 + wm*64 + ((lane >> 4) << 2);
    #pragma unroll
    for (int j = 0; j < 4; ++j) {
        const int e  = colb + j*16;
        const float be = bias[e];
        const int hh = e >> 6, dh = e & 63;
        #pragma unroll
        for (int i = 0; i < 4; ++i) {
            #pragma unroll
            for (int r = 0; r < 4; ++r) {
                const int m = rowb + i*16 + r;
                float v = (acc[i][j][r] + be) * scale;
                if (rmask[m]) v = 0.f;
                if (emode == 0) {
                    outf[(size_t)m*DD + e] = v;
                } else {
                    u16 hb = f2bf(v);
                    u16 lb = f2bf(v - bf2f(hb));
                    const int b2 = m >> 11, s2 = m & (SS-1);
                    size_t idx = (emode == 1)
                        ? ((((size_t)b2*HH + hh)*SS + s2)*DHH + dh)
                        : ((((size_t)b2*HH + hh)*DHH + dh)*SS + s2);
                    out_hi[idx] = hb; out_lo[idx] = lb;
                }
            }
        }
    }
}

__global__ __launch_bounds__(256)
void proj_qkv_mfma(const float* __restrict__ query,
                   const float* __restrict__ key,
                   const float* __restrict__ value,
                   const float* __restrict__ Wq, const float* __restrict__ bq,
                   const float* __restrict__ Wk, const float* __restrict__ bk,
                   const float* __restrict__ Wv, const float* __restrict__ bv,
                   const u8* __restrict__ q_mask, const u8* __restrict__ kv_mask,
                   u16* __restrict__ q_hi, u16* __restrict__ q_lo,
                   u16* __restrict__ k_hi, u16* __restrict__ k_lo,
                   u16* __restrict__ vT_hi, u16* __restrict__ vT_lo)
{
    const int z = blockIdx.z;
    const float* X   = (z==0)? query : (z==1)? key : value;
    const float* W   = (z==0)? Wq    : (z==1)? Wk  : Wv;
    const float* bia = (z==0)? bq    : (z==1)? bk  : bv;
    const u8* pm     = (z==0)? q_mask : kv_mask;
    u16* hi = (z==0)? q_hi : (z==1)? k_hi : vT_hi;
    u16* lo = (z==0)? q_lo : (z==1)? k_lo : vT_lo;
    const float scale = (z==0)? 0.125f : 1.0f;
    const int emode = (z==2)? 2 : 1;
    gemm_core(X, W, bia, pm, scale, blockIdx.y*128, blockIdx.x*128, emode,
              (float*)0, hi, lo);
}

__global__ __launch_bounds__(256)
void proj_out_mfma(const float* __restrict__ xbuf,
                   const float* __restrict__ Wo, const float* __restrict__ bo,
                   const u8* __restrict__ q_mask,
                   float* __restrict__ outp)
{
    gemm_core(xbuf, Wo, bo, q_mask, 1.0f, blockIdx.y*128, blockIdx.x*128, 0,
              outp, (u16*)0, (u16*)0);
}

// ======================================================================
// Fused attention: per (q-tile 64, bh) block, 4 waves column-split.
// Pass A: QK^T (bf16-split MFMA) + rel + mask -> online row max/sum.
// Pass B: recompute QK^T, p = exp(s-m)/l, write attn (coalesced),
//         A@V via MFMA (P staged bf16 hi/lo in LDS, V transposed),
//         rel-V via 33 buckets. Writes x.
// ======================================================================
__global__ __launch_bounds__(256)
void attn_fused(const u16* __restrict__ q_hi, const u16* __restrict__ q_lo,
                const u16* __restrict__ k_hi, const u16* __restrict__ k_lo,
                const u16* __restrict__ vT_hi, const u16* __restrict__ vT_lo,
                const float* __restrict__ wk_emb, const float* __restrict__ wv_emb,
                const u8* __restrict__ kv_mask, const int* __restrict__ use_sub_p,
                float* __restrict__ attn, float* __restrict__ xbuf)
{
    const int qt = blockIdx.x, bh = blockIdx.y;
    const int b = bh >> 4, h = bh & 15;
    const int use_sub = *use_sub_p;
    const int t = threadIdx.x;
    const int lane = t & 63, w = t >> 6;
    const int lg = lane >> 4, ll = lane & 15;

    __shared__ __align__(16) u16 Pbuf[2][64][72];   // hi/lo planes (18.4KB)
    __shared__ float qw_s[64][36];
    __shared__ float wv_s[NR][DHH];
    __shared__ float red_s[4][64][2];
    __shared__ float mid_s[64][36];                 // wk staging, then mid
    __shared__ float stat_s[64][2];

    const int q0 = qt*64;
    const size_t qrow0 = (size_t)bh*SS + q0;
    float* attn_base = attn + ((size_t)bh*SS + q0)*SS;

    // ---- stage Q tile (hi/lo) into Pbuf; wk_emb into mid_s; wv_emb ----
    for (int idx = t; idx < 64*8; idx += 256) {
        int r = idx >> 3, c8 = idx & 7;
        *(short8v*)&Pbuf[0][r][c8*8] = *(const short8v*)&q_hi[(qrow0 + r)*DHH + c8*8];
        *(short8v*)&Pbuf[1][r][c8*8] = *(const short8v*)&q_lo[(qrow0 + r)*DHH + c8*8];
    }
    float* wkf = &mid_s[0][0];   // 2112 floats fit in 64*36=2304
    for (int idx = t; idx < (NR*DHH)/4; idx += 256)
        ((float4*)wkf)[idx] = ((const float4*)wk_emb)[idx];
    for (int idx = t; idx < (NR*DHH)/4; idx += 256)
        ((float4*)&wv_s[0][0])[idx] = ((const float4*)wv_emb)[idx];
    __syncthreads();

    // ---- qw[q][p] = q . wk_emb[p]  (q reconstructed hi+lo) ----
    for (int idx = t; idx < 64*NR; idx += 256) {
        int q = idx & 63, p = idx >> 6;
        float s = 0.f;
        #pragma unroll 8
        for (int d = 0; d < DHH; ++d) {
            float qv = bf2f(Pbuf[0][q][d]) + bf2f(Pbuf[1][q][d]);
            s = fmaf(qv, wkf[p*DHH + d], s);
        }
        qw_s[q][p] = s;
    }
    // ---- Q A-fragments from LDS (resident for both passes) ----
    short8v qa_h[4][2], qa_l[4][2];
    #pragma unroll
    for (int i = 0; i < 4; ++i)
        #pragma unroll
        for (int c = 0; c < 2; ++c) {
            qa_h[i][c] = *(short8v*)&Pbuf[0][16*i + ll][c*32 + lg*8];
            qa_l[i][c] = *(short8v*)&Pbuf[1][16*i + ll][c*32 + lg*8];
        }
    __syncthreads();   // qw_s ready; Pbuf free

    const int vtmax = use_sub ? qt : (NT-1);
    const int vcol  = 16*w + ll;

    // ---- zero-fill strictly-upper attn tiles (no barriers needed) ----
    if (use_sub) {
        const float4 z4 = make_float4(0.f,0.f,0.f,0.f);
        const int row = t >> 2, cg = (t & 3)*16;
        for (int vt = qt+1; vt < NT; ++vt) {
            float* tb = attn_base + vt*64;
            #pragma unroll
            for (int u2 = 0; u2 < 4; ++u2)
                st4(tb + (size_t)row*SS + cg + u2*4, z4);
        }
    }

    // ================= Pass A: online row stats =================
    float rm[4][4], rl[4][4];
    #pragma unroll
    for (int i=0;i<4;++i)
        #pragma unroll
        for (int r=0;r<4;++r){ rm[i][r]=-INFINITY; rl[i][r]=0.f; }

    for (int vt = 0; vt <= vtmax; ++vt) {
        const size_t vrow = (size_t)bh*SS + vt*64 + vcol;
        short8v kb_h[2], kb_l[2];
        #pragma unroll
        for (int c=0;c<2;++c){
            kb_h[c] = *(const short8v*)&k_hi[vrow*DHH + c*32 + lg*8];
            kb_l[c] = *(const short8v*)&k_lo[vrow*DHH + c*32 + lg*8];
        }
        f32x4 acc[4];
        #pragma unroll
        for (int i=0;i<4;++i) acc[i]=(f32x4){0.f,0.f,0.f,0.f};
        #pragma unroll
        for (int c=0;c<2;++c)
            #pragma unroll
            for (int i=0;i<4;++i){
                acc[i] = __builtin_amdgcn_mfma_f32_16x16x32_bf16(qa_h[i][c], kb_h[c], acc[i],0,0,0);
                acc[i] = __builtin_amdgcn_mfma_f32_16x16x32_bf16(qa_h[i][c], kb_l[c], acc[i],0,0,0);
                acc[i] = __builtin_amdgcn_mfma_f32_16x16x32_bf16(qa_l[i][c], kb_h[c], acc[i],0,0,0);
            }
        const int vglob = vt*64 + vcol;
        const bool colmask = (!use_sub) && (kv_mask[b*SS + vglob] != 0);
        #pragma unroll
        for (int i=0;i<4;++i)
            #pragma unroll
            for (int r=0;r<4;++r){
                const int qloc = 16*i + 4*lg + r;
                const int qglob = q0 + qloc;
                int d = vglob - qglob; d = d<-RK?-RK:(d>RK?RK:d);
                float s = acc[i][r] + qw_s[qloc][d+RK];
                const bool msk = use_sub ? (vglob > qglob) : colmask;
                if (msk) s = -INFINITY;
                float mn = fmaxf(rm[i][r], s);
                if (mn > -INFINITY) {
                    rl[i][r] = rl[i][r]*__expf(rm[i][r]-mn) + __expf(s-mn);
                    rm[i][r] = mn;
                }
            }
    }
    // reduce over the 16-lane column group, then across waves
    #pragma unroll
    for (int i=0;i<4;++i)
        #pragma unroll
        for (int r=0;r<4;++r){
            float m = rm[i][r], l = rl[i][r];
            #pragma unroll
            for (int off=1; off<16; off<<=1){
                float om = __shfl_xor(m, off);
                float ol = __shfl_xor(l, off);
                float mn = fmaxf(m, om);
                float e1 = (m  > -INFINITY)? __expf(m  - mn) : 0.f;
                float e2 = (om > -INFINITY)? __expf(om - mn) : 0.f;
                l = l*e1 + ol*e2; m = mn;
            }
            if (ll == 0) { const int qloc = 16*i + 4*lg + r;
                red_s[w][qloc][0] = m; red_s[w][qloc][1] = l; }
        }
    __syncthreads();
    if (t < 64) {
        float m = red_s[0][t][0], l = red_s[0][t][1];
        #pragma unroll
        for (int w2=1; w2<4; ++w2){
            float om = red_s[w2][t][0], ol = red_s[w2][t][1];
            float mn = fmaxf(m, om);
            float e1 = (m >-INFINITY)? __expf(m -mn) : 0.f;
            float e2 = (om>-INFINITY)? __expf(om-mn) : 0.f;
            l = l*e1 + ol*e2; m = mn;
        }
        stat_s[t][0] = m; stat_s[t][1] = 1.f/l;
    }
    __syncthreads();

    // ================= Pass B: attn write + A@V =================
    float pb0[4][4], pb32[4][4];
    #pragma unroll
    for (int i=0;i<4;++i)
        #pragma unroll
        for (int r=0;r<4;++r){ pb0[i][r]=0.f; pb32[i][r]=0.f; }
    f32x4 xac[4];
    #pragma unroll
    for (int i=0;i<4;++i) xac[i]=(f32x4){0.f,0.f,0.f,0.f};

    for (int vt = 0; vt <= vtmax; ++vt) {
        const size_t vrow = (size_t)bh*SS + vt*64 + vcol;
        short8v kb_h[2], kb_l[2];
        #pragma unroll
        for (int c=0;c<2;++c){
            kb_h[c] = *(const short8v*)&k_hi[vrow*DHH + c*32 + lg*8];
            kb_l[c] = *(const short8v*)&k_lo[vrow*DHH + c*32 + lg*8];
        }
        f32x4 acc[4];
        #pragma unroll
        for (int i=0;i<4;++i) acc[i]=(f32x4){0.f,0.f,0.f,0.f};
        #pragma unroll
        for (int c=0;c<2;++c)
            #pragma unroll
            for (int i=0;i<4;++i){
                acc[i] = __builtin_amdgcn_mfma_f32_16x16x32_bf16(qa_h[i][c], kb_h[c], acc[i],0,0,0);
                acc[i] = __builtin_amdgcn_mfma_f32_16x16x32_bf16(qa_h[i][c], kb_l[c], acc[i],0,0,0);
                acc[i] = __builtin_amdgcn_mfma_f32_16x16x32_bf16(qa_l[i][c], kb_h[c], acc[i],0,0,0);
            }
        const int vglob = vt*64 + vcol;
        const bool colmask = (!use_sub) && (kv_mask[b*SS + vglob] != 0);

        __syncthreads();   // previous iteration's Pbuf readers done
        #pragma unroll
        for (int i=0;i<4;++i)
            #pragma unroll
            for (int r=0;r<4;++r){
                const int qloc = 16*i + 4*lg + r;
                const int qglob = q0 + qloc;
                int d = vglob - qglob; d = d<-RK?-RK:(d>RK?RK:d);
                float s = acc[i][r] + qw_s[qloc][d+RK];
                const bool msk = use_sub ? (vglob > qglob) : colmask;
                float p = msk ? 0.f : __expf(s - stat_s[qloc][0]) * stat_s[qloc][1];
                u16 hb = f2bf(p);
                Pbuf[0][qloc][vcol] = hb;
                Pbuf[1][qloc][vcol] = f2bf(p - bf2f(hb));
                if (vglob <= qglob - RK)      pb0[i][r]  += p;
                else if (vglob >= qglob + RK) pb32[i][r] += p;
            }
        __syncthreads();   // Pbuf ready

        // coalesced attn write (reconstruct hi+lo)
        {
            float* tb = attn_base + vt*64;
            const int row = t >> 2, cg = (t & 3)*16;
            #pragma unroll
            for (int u2=0; u2<4; ++u2){
                const int c0 = cg + u2*4;
                float4 o;
                o.x = bf2f(Pbuf[0][row][c0+0]) + bf2f(Pbuf[1][row][c0+0]);
                o.y = bf2f(Pbuf[0][row][c0+1]) + bf2f(Pbuf[1][row][c0+1]);
                o.z = bf2f(Pbuf[0][row][c0+2]) + bf2f(Pbuf[1][row][c0+2]);
                o.w = bf2f(Pbuf[0][row][c0+3]) + bf2f(Pbuf[1][row][c0+3]);
                st4(tb + (size_t)row*SS + c0, o);
            }
        }
        // A@V: wave w owns d-cols [16w,16w+16)
        {
            const size_t dvrow = ((size_t)bh*DHH + 16*w + ll)*SS + (size_t)vt*64;
            short8v vb_h[2], vb_l[2];
            #pragma unroll
            for (int c=0;c<2;++c){
                vb_h[c] = *(const short8v*)&vT_hi[dvrow + c*32 + lg*8];
                vb_l[c] = *(const short8v*)&vT_lo[dvrow + c*32 + lg*8];
            }
            #pragma unroll
            for (int i=0;i<4;++i){
                #pragma unroll
                for (int c=0;c<2;++c){
                    short8v pa_h = *(short8v*)&Pbuf[0][16*i + ll][c*32 + lg*8];
                    short8v pa_l = *(short8v*)&Pbuf[1][16*i + ll][c*32 + lg*8];
                    xac[i] = __builtin_amdgcn_mfma_f32_16x16x32_bf16(pa_h, vb_h[c], xac[i],0,0,0);
                    xac[i] = __builtin_amdgcn_mfma_f32_16x16x32_bf16(pa_h, vb_l[c], xac[i],0,0,0);
                    xac[i] = __builtin_amdgcn_mfma_f32_16x16x32_bf16(pa_l, vb_h[c], xac[i],0,0,0);
                }
            }
        }
    }

    // ---- bucket reduce + band gather ----
    #pragma unroll
    for (int i=0;i<4;++i)
        #pragma unroll
        for (int r=0;r<4;++r){
            float a0 = pb0[i][r], a2 = pb32[i][r];
            #pragma unroll
            for (int off=1; off<16; off<<=1){
                a0 += __shfl_xor(a0, off);
                a2 += __shfl_xor(a2, off);
            }
            if (ll == 0){ const int qloc = 16*i + 4*lg + r;
                red_s[w][qloc][0] = a0; red_s[w][qloc][1] = a2; }
        }
    __threadfence_block();
    __syncthreads();
    if (t < 64) {
        mid_s[t][0]  = red_s[0][t][0]+red_s[1][t][0]+red_s[2][t][0]+red_s[3][t][0];
        mid_s[t][32] = red_s[0][t][1]+red_s[1][t][1]+red_s[2][t][1]+red_s[3][t][1];
        const int qglob = q0 + t;
        const float* rowp = attn_base + (size_t)t*SS;
        #pragma unroll 4
        for (int p=1; p<32; ++p){
            const int v = qglob - RK + p;
            mid_s[t][p] = (v >= 0 && v < SS) ? rowp[v] : 0.f;
        }
    }
    // stage x tile into Pbuf viewed as float[64][66]
    float* xs = reinterpret_cast<float*>(&Pbuf[0][0][0]);
    #pragma unroll
    for (int i=0;i<4;++i)
        #pragma unroll
        for (int r=0;r<4;++r)
            xs[(16*i + 4*lg + r)*66 + 16*w + ll] = xac[i][r];
    __syncthreads();

    // ---- rel-V add + coalesced x write ----
    {
        const int row = t >> 2, dg = (t & 3)*16;
        float av[16];
        #pragma unroll
        for (int e=0;e<16;++e) av[e] = xs[row*66 + dg + e];
        #pragma unroll 4
        for (int p=0; p<NR; ++p){
            const float mm = mid_s[row][p];
            #pragma unroll
            for (int u2=0; u2<4; ++u2){
                float4 w4 = ld4(&wv_s[p][dg + u2*4]);
                av[u2*4+0] = fmaf(mm, w4.x, av[u2*4+0]);
                av[u2*4+1] = fmaf(mm, w4.y, av[u2*4+1]);
                av[u2*4+2] = fmaf(mm, w4.z, av[u2*4+2]);
                av[u2*4+3] = fmaf(mm, w4.w, av[u2*4+3]);
            }
        }
        float* xg = xbuf + ((size_t)(b*SS + q0 + row))*DD + h*DHH + dg;
        #pragma unroll
        for (int u2=0; u2<4; ++u2)
            st4(xg + u2*4, make_float4(av[u2*4+0],av[u2*4+1],av[u2*4+2],av[u2*4+3]));
    }
}

extern "C" void kernel_launch(void* const* d_in, const int* in_sizes, int n_in,
                              void* d_out, int out_size, void* d_ws, size_t ws_size,
                              hipStream_t stream)
{
    const float* query = (const float*)d_in[0];
    const float* key_  = (const float*)d_in[1];
    const float* value = (const float*)d_in[2];
    const u8*    q_mask  = (const u8*)d_in[3];
    const u8*    kv_mask = (const u8*)d_in[4];
    const int*   use_sub = (const int*)d_in[5];
    const float* Wq = (const float*)d_in[6];  const float* bq = (const float*)d_in[7];
    const float* Wk = (const float*)d_in[8];  const float* bk = (const float*)d_in[9];
    const float* Wv = (const float*)d_in[10]; const float* bv = (const float*)d_in[11];
    const float* Wo = (const float*)d_in[12]; const float* bo = (const float*)d_in[13];
    const float* wk_emb = (const float*)d_in[14];
    const float* wv_emb = (const float*)d_in[15];

    float* outp = (float*)d_out;
    float* attn = outp + (size_t)MT*DD;

    u16* wsu   = (u16*)d_ws;
    u16* q_hi  = wsu;          u16* q_lo  = wsu + NF;
    u16* k_hi  = wsu + 2*NF;   u16* k_lo  = wsu + 3*NF;
    u16* vT_hi = wsu + 4*NF;   u16* vT_lo = wsu + 5*NF;
    float* xbuf = (float*)(wsu + 6*NF);

    proj_qkv_mfma<<<dim3(8,32,3), 256, 0, stream>>>(
        query, key_, value, Wq, bq, Wk, bk, Wv, bv, q_mask, kv_mask,
        q_hi, q_lo, k_hi, k_lo, vT_hi, vT_lo);
    attn_fused<<<dim3(NT,BH), 256, 0, stream>>>(
        q_hi, q_lo, k_hi, k_lo, vT_hi, vT_lo,
        wk_emb, wv_emb, kv_mask, use_sub, attn, xbuf);
    proj_out_mfma<<<dim3(8,32), 256, 0, stream>>>(xbuf, Wo, bo, q_mask, outp);
}

// Round 7
// 1282.617 us; speedup vs baseline: 1.3905x; 1.1065x over previous
//
#include <hip/hip_runtime.h>
#include <math.h>

#define BB  2
#define SS  2048
#define DD  1024
#define HH  16
#define DHH 64
#define RK  16
#define NR  33          // 2*RK+1
#define BH  (BB*HH)     // 32
#define MT  (BB*SS)     // 4096
#define NT  (SS/64)     // 32
#define NF  ((size_t)BH*SS*DHH)   // 4,194,304 elements
#define WN  (DD*DD)               // 1,048,576

typedef unsigned char u8;
typedef unsigned short u16;
typedef __attribute__((ext_vector_type(8))) short short8v;
typedef __attribute__((ext_vector_type(4))) float f32x4;

__device__ __forceinline__ float4 ld4(const float* p){ return *reinterpret_cast<const float4*>(p); }
__device__ __forceinline__ void st4(float* p, float4 v){ *reinterpret_cast<float4*>(p) = v; }

__device__ __forceinline__ u16 f2bf(float f){
    union { float f; unsigned u; } v; v.f = f;
    unsigned r = v.u + 0x7fffu + ((v.u >> 16) & 1u);   // RNE
    return (u16)(r >> 16);
}
__device__ __forceinline__ float bf2f(u16 h){
    union { unsigned u; float f; } v; v.u = ((unsigned)h) << 16;
    return v.f;
}

__device__ __forceinline__ void gload_lds16(const void* g, void* l){
    __builtin_amdgcn_global_load_lds(
        (const __attribute__((address_space(1))) void*)g,
        (__attribute__((address_space(3))) void*)l, 16, 0, 0);
}

// ---------------- W pre-split: fp32 -> bf16 hi/lo planes ----------------
__global__ __launch_bounds__(256)
void conv_w_kernel(const float* __restrict__ Wq, const float* __restrict__ Wk,
                   const float* __restrict__ Wv, const float* __restrict__ Wo,
                   u16* __restrict__ wpl)
{
    const int z = blockIdx.y;
    const float* W = (z==0)? Wq : (z==1)? Wk : (z==2)? Wv : Wo;
    u16* hi = wpl + (size_t)z*2*WN;
    u16* lo = hi + WN;
    const int idx = (blockIdx.x*256 + threadIdx.x)*4;
    float4 x = ld4(W + idx);
    ushort4 h, l;
    h.x = f2bf(x.x); l.x = f2bf(x.x - bf2f(h.x));
    h.y = f2bf(x.y); l.y = f2bf(x.y - bf2f(h.y));
    h.z = f2bf(x.z); l.z = f2bf(x.z - bf2f(h.z));
    h.w = f2bf(x.w); l.w = f2bf(x.w - bf2f(h.w));
    *(ushort4*)&hi[idx] = h;
    *(ushort4*)&lo[idx] = l;
}

// ======================================================================
// bf16-split MFMA GEMM: C[m][e] = sum_d A[m,d]*B[e,d]; 128x128 tile BK=64.
// B always pre-split planes via global_load_lds (swizzled slots).
// AMODE 0: A = fp32 [m][DD], convert in staging.  AMODE 1: A = pre-split
// planes in head-layout ((b*HH+hh)*SS+s)*DHH+dh via global_load_lds.
// emode: 0 fp32 out[m][DD]; 1 u16 hi/lo (bh,s,dh); 2 u16 hi/lo (bh,dh,s).
// LDS slot for (row r, kgroup kg of 8): r*8 + (kg ^ (r&7))  [T2 swizzle]
// ======================================================================
template<int AMODE>
__device__ __forceinline__ void gemm2_core(
    const float* __restrict__ Af,
    const u16* A_hi, const u16* A_lo,
    const u16* __restrict__ B_hi, const u16* __restrict__ B_lo,
    const float* __restrict__ bias, const u8* __restrict__ rmask,
    float scale, int m0, int n0, int emode,
    float* __restrict__ outf, u16* o_hi, u16* o_lo)
{
    __shared__ short8v buf[4096];   // 64 KiB: [Ah|Al|Bh|Bl] x 1024 units
    const int t    = threadIdx.x;
    const int lane = t & 63;
    const int w    = t >> 6;
    const int wm   = w >> 1, wn = w & 1;
    const int ll   = lane & 15, lg = lane >> 4;

    f32x4 acc[4][4];
    #pragma unroll
    for (int i=0;i<4;++i)
        #pragma unroll
        for (int j=0;j<4;++j) acc[i][j] = (f32x4){0.f,0.f,0.f,0.f};

    for (int k0 = 0; k0 < DD; k0 += 64) {
        __syncthreads();
        // ---- B staging: global_load_lds, pre-swizzled source ----
        #pragma unroll
        for (int p = 0; p < 2; ++p) {
            const u16* src = p ? B_lo : B_hi;
            #pragma unroll
            for (int j = 0; j < 4; ++j) {
                const int u = j*256 + t;
                const int r = u >> 3, kg = (u & 7) ^ (r & 7);
                const u16* gp = src + (size_t)(n0 + r)*DD + k0 + kg*8;
                gload_lds16(gp, &buf[(2+p)*1024 + j*256 + w*64]);
            }
        }
        // ---- A staging ----
        if (AMODE == 0) {
            #pragma unroll
            for (int j = 0; j < 4; ++j) {
                const int u = j*256 + t;
                const int r = u >> 3, kg = u & 7;
                const float* gp = Af + (size_t)(m0 + r)*DD + k0 + kg*8;
                float4 x0 = ld4(gp), x1 = ld4(gp + 4);
                float xs[8] = {x0.x,x0.y,x0.z,x0.w,x1.x,x1.y,x1.z,x1.w};
                short8v h, l;
                #pragma unroll
                for (int e = 0; e < 8; ++e) {
                    u16 hu = f2bf(xs[e]);
                    h[e] = (short)hu;
                    l[e] = (short)f2bf(xs[e] - bf2f(hu));
                }
                const int slot = r*8 + (kg ^ (r & 7));
                buf[slot] = h; buf[1024 + slot] = l;
            }
        } else {
            #pragma unroll
            for (int p = 0; p < 2; ++p) {
                const u16* src = p ? A_lo : A_hi;
                #pragma unroll
                for (int j = 0; j < 4; ++j) {
                    const int u = j*256 + t;
                    const int r = u >> 3, kg = (u & 7) ^ (r & 7);
                    const int m = m0 + r, b2 = m >> 11, s2 = m & (SS-1);
                    const u16* gp = src + (((size_t)b2*HH + (k0 >> 6))*SS + s2)*DHH + kg*8;
                    gload_lds16(gp, &buf[p*1024 + j*256 + w*64]);
                }
            }
        }
        __syncthreads();
        // ---- MFMA ----
        #pragma unroll
        for (int c = 0; c < 2; ++c) {
            short8v ah[4], al[4], bh2[4], bl2[4];
            #pragma unroll
            for (int i = 0; i < 4; ++i) {
                const int ar = wm*64 + i*16 + ll;
                const int as = ar*8 + ((c*4 + lg) ^ (ar & 7));
                ah[i] = buf[as]; al[i] = buf[1024 + as];
                const int br = wn*64 + i*16 + ll;
                const int bs = br*8 + ((c*4 + lg) ^ (br & 7));
                bh2[i] = buf[2048 + bs]; bl2[i] = buf[3072 + bs];
            }
            #pragma unroll
            for (int i = 0; i < 4; ++i)
                #pragma unroll
                for (int j = 0; j < 4; ++j) {
                    acc[i][j] = __builtin_amdgcn_mfma_f32_16x16x32_bf16(ah[i], bh2[j], acc[i][j], 0,0,0);
                    acc[i][j] = __builtin_amdgcn_mfma_f32_16x16x32_bf16(ah[i], bl2[j], acc[i][j], 0,0,0);
                    acc[i][j] = __builtin_amdgcn_mfma_f32_16x16x32_bf16(al[i], bh2[j], acc[i][j], 0,0,0);
                }
        }
    }

    // ---- epilogue: LDS bounce for coalesced stores ----
    const int lg4 = lg << 2;
    if (emode == 0) {
        float* lb = (float*)&buf[0];   // [64][132]
        #pragma unroll
        for (int h2 = 0; h2 < 2; ++h2) {
            __syncthreads();
            if (wm == h2) {
                #pragma unroll
                for (int i = 0; i < 4; ++i)
                    #pragma unroll
                    for (int j = 0; j < 4; ++j)
                        #pragma unroll
                        for (int r = 0; r < 4; ++r) {
                            const int row = i*16 + lg4 + r;
                            const int col = wn*64 + ll + j*16;
                            const int m = m0 + h2*64 + row;
                            float v = (acc[i][j][r] + bias[n0+col]) * scale;
                            if (rmask[m]) v = 0.f;
                            lb[row*132 + col] = v;
                        }
            }
            __syncthreads();
            const int r2 = t >> 2, qd = t & 3;
            const int m = m0 + h2*64 + r2;
            float* dst = outf + (size_t)m*DD + n0 + qd*32;
            const float* src = &lb[r2*132 + qd*32];
            #pragma unroll
            for (int k = 0; k < 8; ++k) st4(dst + k*4, ld4(src + k*4));
        }
    } else if (emode == 1) {
        u16* lh  = (u16*)&buf[0];      // [64][136]
        u16* lo2 = lh + 64*136;
        #pragma unroll
        for (int h2 = 0; h2 < 2; ++h2) {
            __syncthreads();
            if (wm == h2) {
                #pragma unroll
                for (int i = 0; i < 4; ++i)
                    #pragma unroll
                    for (int j = 0; j < 4; ++j)
                        #pragma unroll
                        for (int r = 0; r < 4; ++r) {
                            const int row = i*16 + lg4 + r;
                            const int col = wn*64 + ll + j*16;
                            const int m = m0 + h2*64 + row;
                            float v = (acc[i][j][r] + bias[n0+col]) * scale;
                            if (rmask[m]) v = 0.f;
                            u16 hb = f2bf(v);
                            lh [row*136 + col] = hb;
                            lo2[row*136 + col] = f2bf(v - bf2f(hb));
                        }
            }
            __syncthreads();
            const int r2 = t >> 2, qd = t & 3;
            const int m = m0 + h2*64 + r2, b2 = m >> 11, s2 = m & (SS-1);
            const int e0g = n0 + qd*32;
            const size_t base = (((size_t)b2*HH + (e0g>>6))*SS + s2)*DHH + (e0g & 63);
            const u16* sh_ = &lh [r2*136 + qd*32];
            const u16* sl_ = &lo2[r2*136 + qd*32];
            #pragma unroll
            for (int k = 0; k < 4; ++k) {
                *(short8v*)&o_hi[base + k*8] = *(const short8v*)&sh_[k*8];
                *(short8v*)&o_lo[base + k*8] = *(const short8v*)&sl_[k*8];
            }
        }
    } else {
        u16* lh  = (u16*)&buf[0];      // [128][72] transposed
        u16* lo2 = lh + 128*72;
        #pragma unroll
        for (int h2 = 0; h2 < 2; ++h2) {
            __syncthreads();
            if (wm == h2) {
                #pragma unroll
                for (int i = 0; i < 4; ++i)
                    #pragma unroll
                    for (int j = 0; j < 4; ++j)
                        #pragma unroll
                        for (int r = 0; r < 4; ++r) {
                            const int row = i*16 + lg4 + r;
                            const int col = wn*64 + ll + j*16;
                            const int m = m0 + h2*64 + row;
                            float v = (acc[i][j][r] + bias[n0+col]) * scale;
                            if (rmask[m]) v = 0.f;
                            u16 hb = f2bf(v);
                            lh [col*72 + row] = hb;
                            lo2[col*72 + row] = f2bf(v - bf2f(hb));
                        }
            }
            __syncthreads();
            const int c2 = t >> 1, mh = t & 1;
            const int e = n0 + c2;
            const int mb = m0 + h2*64 + mh*32, b2 = mb >> 11, s0 = mb & (SS-1);
            const size_t base = (((size_t)b2*HH + (e>>6))*DHH + (e & 63))*SS + s0;
            const u16* sh_ = &lh [c2*72 + mh*32];
            const u16* sl_ = &lo2[c2*72 + mh*32];
            #pragma unroll
            for (int k = 0; k < 4; ++k) {
                *(short8v*)&o_hi[base + k*8] = *(const short8v*)&sh_[k*8];
                *(short8v*)&o_lo[base + k*8] = *(const short8v*)&sl_[k*8];
            }
        }
    }
}

__global__ __launch_bounds__(256)
void proj_in_kernel(const float* __restrict__ query, const float* __restrict__ key,
                    const float* __restrict__ value, const u16* __restrict__ wpl,
                    const float* __restrict__ bq, const float* __restrict__ bk,
                    const float* __restrict__ bv,
                    const u8* __restrict__ q_mask, const u8* __restrict__ kv_mask,
                    u16* q_hi, u16* q_lo, u16* k_hi, u16* k_lo,
                    u16* vT_hi, u16* vT_lo)
{
    const int z = blockIdx.z;
    const float* X    = (z==0)? query : (z==1)? key : value;
    const u16* B_hi   = wpl + (size_t)z*2*WN;
    const u16* B_lo   = B_hi + WN;
    const float* bias = (z==0)? bq : (z==1)? bk : bv;
    const u8* pm      = (z==0)? q_mask : kv_mask;
    u16* ohi = (z==0)? q_hi : (z==1)? k_hi : vT_hi;
    u16* olo = (z==0)? q_lo : (z==1)? k_lo : vT_lo;
    gemm2_core<0>(X, (const u16*)0, (const u16*)0, B_hi, B_lo, bias, pm,
                  (z==0)? 0.125f : 1.0f, blockIdx.y*128, blockIdx.x*128,
                  (z==2)? 2 : 1, (float*)0, ohi, olo);
}

__global__ __launch_bounds__(256)
void proj_out_kernel2(const u16* x_hi, const u16* x_lo, const u16* __restrict__ wpl,
                      const float* __restrict__ bo, const u8* __restrict__ q_mask,
                      float* __restrict__ outp)
{
    gemm2_core<1>((const float*)0, x_hi, x_lo,
                  wpl + (size_t)3*2*WN, wpl + (size_t)3*2*WN + WN,
                  bo, q_mask, 1.0f, blockIdx.y*128, blockIdx.x*128, 0,
                  outp, (u16*)0, (u16*)0);
}

// ======================================================================
// Fused attention (unchanged math from round 4).  x is now written as
// bf16 hi/lo planes ALIASED onto the q planes (region-exclusive: each
// block reads only its own q tile at start, writes the same region at end).
// ======================================================================
__global__ __launch_bounds__(256)
void attn_fused(const u16* q_hi, const u16* q_lo,
                const u16* __restrict__ k_hi, const u16* __restrict__ k_lo,
                const u16* __restrict__ vT_hi, const u16* __restrict__ vT_lo,
                const float* __restrict__ wk_emb, const float* __restrict__ wv_emb,
                const u8* __restrict__ kv_mask, const int* __restrict__ use_sub_p,
                float* __restrict__ attn, u16* x_hi, u16* x_lo)
{
    const int qt = blockIdx.x, bh = blockIdx.y;
    const int b = bh >> 4;
    const int use_sub = *use_sub_p;
    const int t = threadIdx.x;
    const int lane = t & 63, w = t >> 6;
    const int lg = lane >> 4, ll = lane & 15;

    __shared__ __align__(16) u16 Pbuf[2][64][72];
    __shared__ float qw_s[64][36];
    __shared__ float wv_s[NR][DHH];
    __shared__ float red_s[4][64][2];
    __shared__ float mid_s[64][36];
    __shared__ float stat_s[64][2];

    const int q0 = qt*64;
    const size_t qrow0 = (size_t)bh*SS + q0;
    float* attn_base = attn + ((size_t)bh*SS + q0)*SS;

    for (int idx = t; idx < 64*8; idx += 256) {
        int r = idx >> 3, c8 = idx & 7;
        *(short8v*)&Pbuf[0][r][c8*8] = *(const short8v*)&q_hi[(qrow0 + r)*DHH + c8*8];
        *(short8v*)&Pbuf[1][r][c8*8] = *(const short8v*)&q_lo[(qrow0 + r)*DHH + c8*8];
    }
    float* wkf = &mid_s[0][0];
    for (int idx = t; idx < (NR*DHH)/4; idx += 256)
        ((float4*)wkf)[idx] = ((const float4*)wk_emb)[idx];
    for (int idx = t; idx < (NR*DHH)/4; idx += 256)
        ((float4*)&wv_s[0][0])[idx] = ((const float4*)wv_emb)[idx];
    __syncthreads();

    for (int idx = t; idx < 64*NR; idx += 256) {
        int q = idx & 63, p = idx >> 6;
        float s = 0.f;
        #pragma unroll 8
        for (int d = 0; d < DHH; ++d) {
            float qv = bf2f(Pbuf[0][q][d]) + bf2f(Pbuf[1][q][d]);
            s = fmaf(qv, wkf[p*DHH + d], s);
        }
        qw_s[q][p] = s;
    }
    short8v qa_h[4][2], qa_l[4][2];
    #pragma unroll
    for (int i = 0; i < 4; ++i)
        #pragma unroll
        for (int c = 0; c < 2; ++c) {
            qa_h[i][c] = *(short8v*)&Pbuf[0][16*i + ll][c*32 + lg*8];
            qa_l[i][c] = *(short8v*)&Pbuf[1][16*i + ll][c*32 + lg*8];
        }
    __syncthreads();

    const int vtmax = use_sub ? qt : (NT-1);
    const int vcol  = 16*w + ll;

    if (use_sub) {
        const float4 z4 = make_float4(0.f,0.f,0.f,0.f);
        const int row = t >> 2, cg = (t & 3)*16;
        for (int vt = qt+1; vt < NT; ++vt) {
            float* tb = attn_base + vt*64;
            #pragma unroll
            for (int u2 = 0; u2 < 4; ++u2)
                st4(tb + (size_t)row*SS + cg + u2*4, z4);
        }
    }

    // ================= Pass A =================
    float rm[4][4], rl[4][4];
    #pragma unroll
    for (int i=0;i<4;++i)
        #pragma unroll
        for (int r=0;r<4;++r){ rm[i][r]=-INFINITY; rl[i][r]=0.f; }

    for (int vt = 0; vt <= vtmax; ++vt) {
        const size_t vrow = (size_t)bh*SS + vt*64 + vcol;
        short8v kb_h[2], kb_l[2];
        #pragma unroll
        for (int c=0;c<2;++c){
            kb_h[c] = *(const short8v*)&k_hi[vrow*DHH + c*32 + lg*8];
            kb_l[c] = *(const short8v*)&k_lo[vrow*DHH + c*32 + lg*8];
        }
        f32x4 acc[4];
        #pragma unroll
        for (int i=0;i<4;++i) acc[i]=(f32x4){0.f,0.f,0.f,0.f};
        #pragma unroll
        for (int c=0;c<2;++c)
            #pragma unroll
            for (int i=0;i<4;++i){
                acc[i] = __builtin_amdgcn_mfma_f32_16x16x32_bf16(qa_h[i][c], kb_h[c], acc[i],0,0,0);
                acc[i] = __builtin_amdgcn_mfma_f32_16x16x32_bf16(qa_h[i][c], kb_l[c], acc[i],0,0,0);
                acc[i] = __builtin_amdgcn_mfma_f32_16x16x32_bf16(qa_l[i][c], kb_h[c], acc[i],0,0,0);
            }
        const int vglob = vt*64 + vcol;
        const bool colmask = (!use_sub) && (kv_mask[b*SS + vglob] != 0);
        #pragma unroll
        for (int i=0;i<4;++i)
            #pragma unroll
            for (int r=0;r<4;++r){
                const int qloc = 16*i + 4*lg + r;
                const int qglob = q0 + qloc;
                int d = vglob - qglob; d = d<-RK?-RK:(d>RK?RK:d);
                float s = acc[i][r] + qw_s[qloc][d+RK];
                const bool msk = use_sub ? (vglob > qglob) : colmask;
                if (msk) s = -INFINITY;
                float mn = fmaxf(rm[i][r], s);
                if (mn > -INFINITY) {
                    rl[i][r] = rl[i][r]*__expf(rm[i][r]-mn) + __expf(s-mn);
                    rm[i][r] = mn;
                }
            }
    }
    #pragma unroll
    for (int i=0;i<4;++i)
        #pragma unroll
        for (int r=0;r<4;++r){
            float m = rm[i][r], l = rl[i][r];
            #pragma unroll
            for (int off=1; off<16; off<<=1){
                float om = __shfl_xor(m, off);
                float ol = __shfl_xor(l, off);
                float mn = fmaxf(m, om);
                float e1 = (m  > -INFINITY)? __expf(m  - mn) : 0.f;
                float e2 = (om > -INFINITY)? __expf(om - mn) : 0.f;
                l = l*e1 + ol*e2; m = mn;
            }
            if (ll == 0) { const int qloc = 16*i + 4*lg + r;
                red_s[w][qloc][0] = m; red_s[w][qloc][1] = l; }
        }
    __syncthreads();
    if (t < 64) {
        float m = red_s[0][t][0], l = red_s[0][t][1];
        #pragma unroll
        for (int w2=1; w2<4; ++w2){
            float om = red_s[w2][t][0], ol = red_s[w2][t][1];
            float mn = fmaxf(m, om);
            float e1 = (m >-INFINITY)? __expf(m -mn) : 0.f;
            float e2 = (om>-INFINITY)? __expf(om-mn) : 0.f;
            l = l*e1 + ol*e2; m = mn;
        }
        stat_s[t][0] = m; stat_s[t][1] = 1.f/l;
    }
    __syncthreads();

    // ================= Pass B =================
    float pb0[4][4], pb32[4][4];
    #pragma unroll
    for (int i=0;i<4;++i)
        #pragma unroll
        for (int r=0;r<4;++r){ pb0[i][r]=0.f; pb32[i][r]=0.f; }
    f32x4 xac[4];
    #pragma unroll
    for (int i=0;i<4;++i) xac[i]=(f32x4){0.f,0.f,0.f,0.f};

    for (int vt = 0; vt <= vtmax; ++vt) {
        const size_t vrow = (size_t)bh*SS + vt*64 + vcol;
        short8v kb_h[2], kb_l[2];
        #pragma unroll
        for (int c=0;c<2;++c){
            kb_h[c] = *(const short8v*)&k_hi[vrow*DHH + c*32 + lg*8];
            kb_l[c] = *(const short8v*)&k_lo[vrow*DHH + c*32 + lg*8];
        }
        f32x4 acc[4];
        #pragma unroll
        for (int i=0;i<4;++i) acc[i]=(f32x4){0.f,0.f,0.f,0.f};
        #pragma unroll
        for (int c=0;c<2;++c)
            #pragma unroll
            for (int i=0;i<4;++i){
                acc[i] = __builtin_amdgcn_mfma_f32_16x16x32_bf16(qa_h[i][c], kb_h[c], acc[i],0,0,0);
                acc[i] = __builtin_amdgcn_mfma_f32_16x16x32_bf16(qa_h[i][c], kb_l[c], acc[i],0,0,0);
                acc[i] = __builtin_amdgcn_mfma_f32_16x16x32_bf16(qa_l[i][c], kb_h[c], acc[i],0,0,0);
            }
        const int vglob = vt*64 + vcol;
        const bool colmask = (!use_sub) && (kv_mask[b*SS + vglob] != 0);

        __syncthreads();
        #pragma unroll
        for (int i=0;i<4;++i)
            #pragma unroll
            for (int r=0;r<4;++r){
                const int qloc = 16*i + 4*lg + r;
                const int qglob = q0 + qloc;
                int d = vglob - qglob; d = d<-RK?-RK:(d>RK?RK:d);
                float s = acc[i][r] + qw_s[qloc][d+RK];
                const bool msk = use_sub ? (vglob > qglob) : colmask;
                float p = msk ? 0.f : __expf(s - stat_s[qloc][0]) * stat_s[qloc][1];
                u16 hb = f2bf(p);
                Pbuf[0][qloc][vcol] = hb;
                Pbuf[1][qloc][vcol] = f2bf(p - bf2f(hb));
                if (vglob <= qglob - RK)      pb0[i][r]  += p;
                else if (vglob >= qglob + RK) pb32[i][r] += p;
            }
        __syncthreads();

        {
            float* tb = attn_base + vt*64;
            const int row = t >> 2, cg = (t & 3)*16;
            #pragma unroll
            for (int u2=0; u2<4; ++u2){
                const int c0 = cg + u2*4;
                float4 o;
                o.x = bf2f(Pbuf[0][row][c0+0]) + bf2f(Pbuf[1][row][c0+0]);
                o.y = bf2f(Pbuf[0][row][c0+1]) + bf2f(Pbuf[1][row][c0+1]);
                o.z = bf2f(Pbuf[0][row][c0+2]) + bf2f(Pbuf[1][row][c0+2]);
                o.w = bf2f(Pbuf[0][row][c0+3]) + bf2f(Pbuf[1][row][c0+3]);
                st4(tb + (size_t)row*SS + c0, o);
            }
        }
        {
            const size_t dvrow = ((size_t)bh*DHH + 16*w + ll)*SS + (size_t)vt*64;
            short8v vb_h[2], vb_l[2];
            #pragma unroll
            for (int c=0;c<2;++c){
                vb_h[c] = *(const short8v*)&vT_hi[dvrow + c*32 + lg*8];
                vb_l[c] = *(const short8v*)&vT_lo[dvrow + c*32 + lg*8];
            }
            #pragma unroll
            for (int i=0;i<4;++i){
                #pragma unroll
                for (int c=0;c<2;++c){
                    short8v pa_h = *(short8v*)&Pbuf[0][16*i + ll][c*32 + lg*8];
                    short8v pa_l = *(short8v*)&Pbuf[1][16*i + ll][c*32 + lg*8];
                    xac[i] = __builtin_amdgcn_mfma_f32_16x16x32_bf16(pa_h, vb_h[c], xac[i],0,0,0);
                    xac[i] = __builtin_amdgcn_mfma_f32_16x16x32_bf16(pa_h, vb_l[c], xac[i],0,0,0);
                    xac[i] = __builtin_amdgcn_mfma_f32_16x16x32_bf16(pa_l, vb_h[c], xac[i],0,0,0);
                }
            }
        }
    }

    #pragma unroll
    for (int i=0;i<4;++i)
        #pragma unroll
        for (int r=0;r<4;++r){
            float a0 = pb0[i][r], a2 = pb32[i][r];
            #pragma unroll
            for (int off=1; off<16; off<<=1){
                a0 += __shfl_xor(a0, off);
                a2 += __shfl_xor(a2, off);
            }
            if (ll == 0){ const int qloc = 16*i + 4*lg + r;
                red_s[w][qloc][0] = a0; red_s[w][qloc][1] = a2; }
        }
    __threadfence_block();
    __syncthreads();
    if (t < 64) {
        mid_s[t][0]  = red_s[0][t][0]+red_s[1][t][0]+red_s[2][t][0]+red_s[3][t][0];
        mid_s[t][32] = red_s[0][t][1]+red_s[1][t][1]+red_s[2][t][1]+red_s[3][t][1];
        const int qglob = q0 + t;
        const float* rowp = attn_base + (size_t)t*SS;
        #pragma unroll 4
        for (int p=1; p<32; ++p){
            const int v = qglob - RK + p;
            mid_s[t][p] = (v >= 0 && v < SS) ? rowp[v] : 0.f;
        }
    }
    float* xs = reinterpret_cast<float*>(&Pbuf[0][0][0]);
    #pragma unroll
    for (int i=0;i<4;++i)
        #pragma unroll
        for (int r=0;r<4;++r)
            xs[(16*i + 4*lg + r)*66 + 16*w + ll] = xac[i][r];
    __syncthreads();

    {
        const int row = t >> 2, dg = (t & 3)*16;
        float av[16];
        #pragma unroll
        for (int e=0;e<16;++e) av[e] = xs[row*66 + dg + e];
        #pragma unroll 4
        for (int p=0; p<NR; ++p){
            const float mm = mid_s[row][p];
            #pragma unroll
            for (int u2=0; u2<4; ++u2){
                float4 w4 = ld4(&wv_s[p][dg + u2*4]);
                av[u2*4+0] = fmaf(mm, w4.x, av[u2*4+0]);
                av[u2*4+1] = fmaf(mm, w4.y, av[u2*4+1]);
                av[u2*4+2] = fmaf(mm, w4.z, av[u2*4+2]);
                av[u2*4+3] = fmaf(mm, w4.w, av[u2*4+3]);
            }
        }
        // x write: bf16 hi/lo planes in q-plane layout (bh, s, dh)
        short8v hv[2], lv[2];
        #pragma unroll
        for (int g=0; g<2; ++g)
            #pragma unroll
            for (int e=0; e<8; ++e){
                float vv = av[g*8+e];
                u16 hb = f2bf(vv);
                hv[g][e] = (short)hb;
                lv[g][e] = (short)f2bf(vv - bf2f(hb));
            }
        const size_t base = ((size_t)bh*SS + q0 + row)*DHH + dg;
        *(short8v*)&x_hi[base]     = hv[0];
        *(short8v*)&x_hi[base + 8] = hv[1];
        *(short8v*)&x_lo[base]     = lv[0];
        *(short8v*)&x_lo[base + 8] = lv[1];
    }
}

extern "C" void kernel_launch(void* const* d_in, const int* in_sizes, int n_in,
                              void* d_out, int out_size, void* d_ws, size_t ws_size,
                              hipStream_t stream)
{
    const float* query = (const float*)d_in[0];
    const float* key_  = (const float*)d_in[1];
    const float* value = (const float*)d_in[2];
    const u8*    q_mask  = (const u8*)d_in[3];
    const u8*    kv_mask = (const u8*)d_in[4];
    const int*   use_sub = (const int*)d_in[5];
    const float* Wq = (const float*)d_in[6];  const float* bq = (const float*)d_in[7];
    const float* Wk = (const float*)d_in[8];  const float* bk = (const float*)d_in[9];
    const float* Wv = (const float*)d_in[10]; const float* bv = (const float*)d_in[11];
    const float* Wo = (const float*)d_in[12]; const float* bo = (const float*)d_in[13];
    const float* wk_emb = (const float*)d_in[14];
    const float* wv_emb = (const float*)d_in[15];

    float* outp = (float*)d_out;
    float* attn = outp + (size_t)MT*DD;

    u16* wsu   = (u16*)d_ws;
    u16* q_hi  = wsu;          u16* q_lo  = wsu + NF;     // also x_hi / x_lo
    u16* k_hi  = wsu + 2*NF;   u16* k_lo  = wsu + 3*NF;
    u16* vT_hi = wsu + 4*NF;   u16* vT_lo = wsu + 5*NF;
    u16* wpl   = wsu + 6*NF;                              // 8 x WN planes

    conv_w_kernel<<<dim3(1024,4), 256, 0, stream>>>(Wq, Wk, Wv, Wo, wpl);
    proj_in_kernel<<<dim3(8,32,3), 256, 0, stream>>>(
        query, key_, value, wpl, bq, bk, bv, q_mask, kv_mask,
        q_hi, q_lo, k_hi, k_lo, vT_hi, vT_lo);
    attn_fused<<<dim3(NT,BH), 256, 0, stream>>>(
        q_hi, q_lo, k_hi, k_lo, vT_hi, vT_lo,
        wk_emb, wv_emb, kv_mask, use_sub, attn, q_hi, q_lo);
    proj_out_kernel2<<<dim3(8,32), 256, 0, stream>>>(
        q_hi, q_lo, wpl, bo, q_mask, outp);
}